// Round 8
// baseline (32.974 us; speedup 1.0000x reference)
//
#include <hip/hip_runtime.h>
#include <math.h>

#define BIGF 1e9f

constexpr int BB = 2, CC = 4, DD = 64, HH = 64, WW = 64;
constexpr int HW   = HH * WW;      // 4096
constexpr int DHW  = DD * HW;      // 262144
constexpr int CDHW = CC * DHW;     // 1048576
constexpr int NTOT = BB * CDHW;    // 2097152
constexpr int NBLK = 512;

// ---------------------------------------------------------------------------
// Kernel A: per block (b,c,d):
//  (0) block 0 zeroes out[0] (B's atomics accumulate into it; stream order
//      guarantees A fully completes before B starts).
//  (1) W-pass (ballot nearest-set-bit) + H-pass (min-plus) for class c of
//      plane (b,d)  ->  dsqT[b][c][h][d][w]  (transposed, 256B-segment stores)
//  (2) softmax probs for h-quarter [16c,16c+16) of plane (b,d), ALL classes
//      ->  probT[b][cc][h][d][w]  (one 256-float4 step for 256 threads).
// ---------------------------------------------------------------------------
__global__ __launch_bounds__(256) void edt_wh_prob(const int* __restrict__ tgt,
                                                   const float* __restrict__ pred,
                                                   float* __restrict__ dsqT,
                                                   float* __restrict__ probT,
                                                   float* __restrict__ out) {
    __shared__ int   ti[HW];   // 16 KB targets slice
    __shared__ float fs[HW];   // 16 KB W-pass result
    const int t   = threadIdx.x;
    const int blk = blockIdx.x;
    if (blk == 0 && t == 0) out[0] = 0.0f;

    const int lane = t & 63;
    const int wv   = t >> 6;
    const int b = blk >> 8;
    const int c = (blk >> 6) & 3;
    const int d = blk & 63;
    const size_t tb = (size_t)(b * 64 + d) * HW;   // tgt[b][d][:][:]

    #pragma unroll
    for (int k = 0; k < 16; ++k) ti[t + k * 256] = tgt[tb + t + k * 256];
    __syncthreads();

    // W-pass: binary input -> squared distance to nearest lane of class c.
    #pragma unroll
    for (int r = 0; r < 16; ++r) {
        const int h = wv * 16 + r;
        const bool isc = (ti[h * 64 + lane] == c);
        const unsigned long long mask = __ballot(isc);
        const unsigned long long mlo  = mask & (~0ull >> (63 - lane));
        const unsigned long long mhi  = mask & (~0ull << lane);
        int dd = 1000;
        if (mlo) dd = lane - (63 - __builtin_clzll(mlo));
        if (mhi) dd = min(dd, (int)__builtin_ctzll(mhi) - lane);
        fs[h * 64 + lane] = (dd >= 1000) ? BIGF : (float)(dd * dd);
    }
    __syncthreads();

    // H-pass: 4(i) x 4(w) register tile per thread.
    const int wg = (t & 15) * 4;
    const int i0 = (t >> 4) * 4;
    float acc[4][4];
    #pragma unroll
    for (int a = 0; a < 4; ++a)
        #pragma unroll
        for (int k = 0; k < 4; ++k) acc[a][k] = BIGF;

    #pragma unroll 8
    for (int j = 0; j < 64; ++j) {
        const float4 v = *reinterpret_cast<const float4*>(&fs[j * 64 + wg]);
        #pragma unroll
        for (int a = 0; a < 4; ++a) {
            const float diff = (float)(i0 + a - j);
            const float cost = diff * diff;
            acc[a][0] = fminf(acc[a][0], v.x + cost);
            acc[a][1] = fminf(acc[a][1], v.y + cost);
            acc[a][2] = fminf(acc[a][2], v.z + cost);
            acc[a][3] = fminf(acc[a][3], v.w + cost);
        }
    }
    const size_t cb = (size_t)(b * 4 + c) * DHW;
    #pragma unroll
    for (int a = 0; a < 4; ++a) {
        const float4 o = make_float4(acc[a][0], acc[a][1], acc[a][2], acc[a][3]);
        *reinterpret_cast<float4*>(&dsqT[cb + (size_t)(i0 + a) * HW + d * 64 + wg]) = o;
    }

    // ---- (2) softmax probs, h-quarter [16c, 16c+16) of plane (b,d) ----
    {
        const int hh = c * 16 + (t >> 4);
        const int w0 = (t & 15) * 4;
        const size_t pidx = (size_t)b * CDHW + (size_t)d * HW + (size_t)hh * 64 + w0;
        const float4 q0 = *reinterpret_cast<const float4*>(&pred[pidx]);
        const float4 q1 = *reinterpret_cast<const float4*>(&pred[pidx + (size_t)DHW]);
        const float4 q2 = *reinterpret_cast<const float4*>(&pred[pidx + 2 * (size_t)DHW]);
        const float4 q3 = *reinterpret_cast<const float4*>(&pred[pidx + 3 * (size_t)DHW]);
        float4 o0, o1, o2, o3;
        #define SMAX(X)                                                          \
        {   const float m = fmaxf(fmaxf(q0.X, q1.X), fmaxf(q2.X, q3.X));         \
            const float e0 = __expf(q0.X - m), e1 = __expf(q1.X - m),            \
                        e2 = __expf(q2.X - m), e3 = __expf(q3.X - m);            \
            const float zinv = 1.0f / (e0 + e1 + e2 + e3);                       \
            o0.X = e0 * zinv; o1.X = e1 * zinv;                                  \
            o2.X = e2 * zinv; o3.X = e3 * zinv; }
        SMAX(x) SMAX(y) SMAX(z) SMAX(w)
        #undef SMAX
        const size_t ob = (size_t)b * CDHW + (size_t)hh * HW + d * 64 + w0;
        *reinterpret_cast<float4*>(&probT[ob])                   = o0;
        *reinterpret_cast<float4*>(&probT[ob + (size_t)DHW])     = o1;
        *reinterpret_cast<float4*>(&probT[ob + 2 * (size_t)DHW]) = o2;
        *reinterpret_cast<float4*>(&probT[ob + 3 * (size_t)DHW]) = o3;
    }
}

// ---------------------------------------------------------------------------
// Kernel B: block = (b,c,h) = linear blk. Stages CONTIGUOUS 16 KB slabs of
// dsqT and probT (both at slab index blk), D min-plus in registers, fused
// prob*sqrt reduce, ONE atomicAdd(out, blocksum/NTOT) per block. No fences.
// ---------------------------------------------------------------------------
__global__ __launch_bounds__(256) void edt_d_reduce(const float* __restrict__ dsqT,
                                                    const float* __restrict__ probT,
                                                    float* __restrict__ out) {
    __shared__ float sdq[HW];   // 16 KB dsq slab [d][w]
    __shared__ float spr[HW];   // 16 KB prob slab [d][w]
    __shared__ float wsum[4];
    const int t   = threadIdx.x;
    const int blk = blockIdx.x;
    const size_t base = (size_t)blk * HW;

    float4 sg[4], pg[4];
    #pragma unroll
    for (int k = 0; k < 4; ++k)
        sg[k] = *reinterpret_cast<const float4*>(&dsqT[base + (size_t)(k * 256 + t) * 4]);
    #pragma unroll
    for (int k = 0; k < 4; ++k)
        pg[k] = *reinterpret_cast<const float4*>(&probT[base + (size_t)(k * 256 + t) * 4]);
    #pragma unroll
    for (int k = 0; k < 4; ++k) {
        *reinterpret_cast<float4*>(&sdq[(k * 256 + t) * 4]) = sg[k];
        *reinterpret_cast<float4*>(&spr[(k * 256 + t) * 4]) = pg[k];
    }
    __syncthreads();

    // D min-plus: 4(i) x 4(w) register tile.
    const int wg = (t & 15) * 4;
    const int i0 = (t >> 4) * 4;
    float acc[4][4];
    #pragma unroll
    for (int a = 0; a < 4; ++a)
        #pragma unroll
        for (int k = 0; k < 4; ++k) acc[a][k] = BIGF;

    #pragma unroll 8
    for (int j = 0; j < 64; ++j) {
        const float4 v = *reinterpret_cast<const float4*>(&sdq[j * 64 + wg]);
        #pragma unroll
        for (int a = 0; a < 4; ++a) {
            const float diff = (float)(i0 + a - j);
            const float cost = diff * diff;
            acc[a][0] = fminf(acc[a][0], v.x + cost);
            acc[a][1] = fminf(acc[a][1], v.y + cost);
            acc[a][2] = fminf(acc[a][2], v.z + cost);
            acc[a][3] = fminf(acc[a][3], v.w + cost);
        }
    }

    // Fused reduce: prob * sqrt(dsq) for this block's 4x4 tile rows.
    float vsum = 0.f;
    #pragma unroll
    for (int a = 0; a < 4; ++a) {
        const float4 pr = *reinterpret_cast<const float4*>(&spr[(i0 + a) * 64 + wg]);
        vsum += pr.x * sqrtf(acc[a][0]) + pr.y * sqrtf(acc[a][1]) +
                pr.z * sqrtf(acc[a][2]) + pr.w * sqrtf(acc[a][3]);
    }
    const int lane = t & 63;
    #pragma unroll
    for (int off = 32; off > 0; off >>= 1) vsum += __shfl_down(vsum, off, 64);
    if (lane == 0) wsum[t >> 6] = vsum;
    __syncthreads();
    if (t == 0)
        atomicAdd(out, (wsum[0] + wsum[1] + wsum[2] + wsum[3]) * (1.0f / (float)NTOT));
}

// ---------------------------------------------------------------------------
extern "C" void kernel_launch(void* const* d_in, const int* in_sizes, int n_in,
                              void* d_out, int out_size, void* d_ws, size_t ws_size,
                              hipStream_t stream) {
    const float* pred = (const float*)d_in[0];
    const int*   tgt  = (const int*)d_in[1];
    float* out   = (float*)d_out;
    float* dsqT  = (float*)d_ws;              // NTOT floats (8 MB)
    float* probT = dsqT + NTOT;               // NTOT floats (8 MB)

    hipLaunchKernelGGL(edt_wh_prob,  dim3(NBLK), dim3(256), 0, stream,
                       tgt, pred, dsqT, probT, out);
    hipLaunchKernelGGL(edt_d_reduce, dim3(NBLK), dim3(256), 0, stream,
                       dsqT, probT, out);
}

// Round 9
// 27.487 us; speedup vs baseline: 1.1996x; 1.1996x over previous
//
#include <hip/hip_runtime.h>
#include <math.h>

typedef unsigned short u16;
typedef unsigned int   u32;
typedef u16 us2 __attribute__((ext_vector_type(2)));

constexpr int BB = 2, CC = 4, DD = 64, HH = 64, WW = 64;
constexpr int HW   = HH * WW;      // 4096
constexpr int DHW  = DD * HW;      // 262144
constexpr int CDHW = CC * DHW;     // 1048576
constexpr int NTOT = BB * CDHW;    // 2097152
constexpr int NBLK = 512;
constexpr u32 SENT = 50000;        // u16 "infinity": 50000+3969+3969 < 65536 (SWAR-safe)

__device__ __forceinline__ u32 pkmin(u32 a, u32 b) {
    us2 r = __builtin_elementwise_min(__builtin_bit_cast(us2, a),
                                      __builtin_bit_cast(us2, b));
    return __builtin_bit_cast(u32, r);
}

// ---------------------------------------------------------------------------
// Kernel A: block = (b,c,d), 512 threads.
//  (1) W-pass: direct coalesced tgt reads + ballot nearest-set-bit -> u16 LDS.
//  (2) H-pass: packed-u16 min-plus, 1 row x 8 w per thread ->
//      dsqT[b][c][h][d][w] (u16, 16B/thread stores).
//  (3) softmax probs for h-quarter [16c,16c+16) of plane (b,d) (threads 0-255)
//      -> probT[b][cc][h][d][w] (f32).
// ---------------------------------------------------------------------------
__global__ __launch_bounds__(512) void edt_wh_prob(const int* __restrict__ tgt,
                                                   const float* __restrict__ pred,
                                                   u16* __restrict__ dsqT,
                                                   float* __restrict__ probT) {
    __shared__ u16 fs[HW];   // 8 KB W-pass result [h][w]
    const int t    = threadIdx.x;
    const int blk  = blockIdx.x;
    const int lane = t & 63;
    const int wv   = t >> 6;           // 8 waves
    const int b = blk >> 8;
    const int c = (blk >> 6) & 3;
    const int d = blk & 63;
    const size_t tb = (size_t)(b * 64 + d) * HW;   // tgt[b][d][:][:]

    // W-pass: 8 rows per wave, ballot nearest-set-bit -> squared dist (int).
    #pragma unroll
    for (int r = 0; r < 8; ++r) {
        const int h   = wv * 8 + r;
        const int cls = tgt[tb + h * 64 + lane];
        const unsigned long long mask = __ballot(cls == c);
        const unsigned long long mlo  = mask & (~0ull >> (63 - lane));
        const unsigned long long mhi  = mask & (~0ull << lane);
        int dd = 1000;
        if (mlo) dd = lane - (63 - __builtin_clzll(mlo));
        if (mhi) dd = min(dd, (int)__builtin_ctzll(mhi) - lane);
        fs[h * 64 + lane] = (dd >= 1000) ? (u16)SENT : (u16)(dd * dd);
    }
    __syncthreads();

    // H-pass: packed u16 min-plus. 1 output row x 8 w per thread.
    const int i  = t >> 3;          // output row 0..63
    const int wg = (t & 7) * 8;     // 8 consecutive w
    u32 a0 = 0xFFFFFFFFu, a1 = 0xFFFFFFFFu, a2 = 0xFFFFFFFFu, a3 = 0xFFFFFFFFu;
    #pragma unroll 8
    for (int j = 0; j < 64; ++j) {
        const uint4 v = *reinterpret_cast<const uint4*>(&fs[j * 64 + wg]);
        const int  diff  = i - j;
        const u32  cost2 = (u32)(diff * diff) * 0x00010001u;  // SWAR pair
        a0 = pkmin(a0, v.x + cost2);
        a1 = pkmin(a1, v.y + cost2);
        a2 = pkmin(a2, v.z + cost2);
        a3 = pkmin(a3, v.w + cost2);
    }
    // dsqT[b][c][h=i][d][w=wg..wg+7]: 8 u16 = one 16B store.
    *reinterpret_cast<uint4*>(&dsqT[((size_t)(b * 4 + c) * 64 + i) * HW + d * 64 + wg])
        = make_uint4(a0, a1, a2, a3);

    // Softmax probs: quarter rows [16c,16c+16), threads 0-255 (one float4 each).
    if (t < 256) {
        const int hh = c * 16 + (t >> 4);
        const int w0 = (t & 15) * 4;
        const size_t pidx = (size_t)b * CDHW + (size_t)d * HW + (size_t)hh * 64 + w0;
        const float4 q0 = *reinterpret_cast<const float4*>(&pred[pidx]);
        const float4 q1 = *reinterpret_cast<const float4*>(&pred[pidx + (size_t)DHW]);
        const float4 q2 = *reinterpret_cast<const float4*>(&pred[pidx + 2 * (size_t)DHW]);
        const float4 q3 = *reinterpret_cast<const float4*>(&pred[pidx + 3 * (size_t)DHW]);
        float4 o0, o1, o2, o3;
        #define SMAX(X)                                                          \
        {   const float m = fmaxf(fmaxf(q0.X, q1.X), fmaxf(q2.X, q3.X));         \
            const float e0 = __expf(q0.X - m), e1 = __expf(q1.X - m),            \
                        e2 = __expf(q2.X - m), e3 = __expf(q3.X - m);            \
            const float zinv = 1.0f / (e0 + e1 + e2 + e3);                       \
            o0.X = e0 * zinv; o1.X = e1 * zinv;                                  \
            o2.X = e2 * zinv; o3.X = e3 * zinv; }
        SMAX(x) SMAX(y) SMAX(z) SMAX(w)
        #undef SMAX
        const size_t ob = (size_t)b * CDHW + (size_t)hh * HW + d * 64 + w0;
        *reinterpret_cast<float4*>(&probT[ob])                   = o0;
        *reinterpret_cast<float4*>(&probT[ob + (size_t)DHW])     = o1;
        *reinterpret_cast<float4*>(&probT[ob + 2 * (size_t)DHW]) = o2;
        *reinterpret_cast<float4*>(&probT[ob + 3 * (size_t)DHW]) = o3;
    }
}

// ---------------------------------------------------------------------------
// Kernel B: block = (b,c,h) = blk, 512 threads. Stages the contiguous 8 KB
// u16 dsq slab [d][w], packed min-plus along d (1 row x 8 w per thread),
// direct prob reads (32 B/thread), fused prob*sqrt reduce, partial store.
// ---------------------------------------------------------------------------
__global__ __launch_bounds__(512) void edt_d_reduce(const u16* __restrict__ dsqT,
                                                    const float* __restrict__ probT,
                                                    float* __restrict__ partial) {
    __shared__ u16   sdq[HW];   // 8 KB slab [d][w]
    __shared__ float wsum[8];
    const int t   = threadIdx.x;
    const int blk = blockIdx.x;
    const size_t base = (size_t)blk * HW;   // u16 units (and float units for probT)

    // Stage 8 KB: exactly one uint4 (8 u16) per thread, fully coalesced.
    reinterpret_cast<uint4*>(sdq)[t] =
        reinterpret_cast<const uint4*>(&dsqT[base])[t];
    __syncthreads();

    const int i  = t >> 3;          // output d-row 0..63
    const int wg = (t & 7) * 8;
    u32 a0 = 0xFFFFFFFFu, a1 = 0xFFFFFFFFu, a2 = 0xFFFFFFFFu, a3 = 0xFFFFFFFFu;
    #pragma unroll 8
    for (int j = 0; j < 64; ++j) {
        const uint4 v = *reinterpret_cast<const uint4*>(&sdq[j * 64 + wg]);
        const int  diff  = i - j;
        const u32  cost2 = (u32)(diff * diff) * 0x00010001u;
        a0 = pkmin(a0, v.x + cost2);
        a1 = pkmin(a1, v.y + cost2);
        a2 = pkmin(a2, v.z + cost2);
        a3 = pkmin(a3, v.w + cost2);
    }

    // Fused reduce: prob[b][c][h][i][wg..] * sqrt(dsq). 8 points per thread.
    const float4 p0 = *reinterpret_cast<const float4*>(&probT[base + i * 64 + wg]);
    const float4 p1 = *reinterpret_cast<const float4*>(&probT[base + i * 64 + wg + 4]);
    float vsum =
        p0.x * sqrtf((float)(a0 & 0xFFFFu)) + p0.y * sqrtf((float)(a0 >> 16)) +
        p0.z * sqrtf((float)(a1 & 0xFFFFu)) + p0.w * sqrtf((float)(a1 >> 16)) +
        p1.x * sqrtf((float)(a2 & 0xFFFFu)) + p1.y * sqrtf((float)(a2 >> 16)) +
        p1.z * sqrtf((float)(a3 & 0xFFFFu)) + p1.w * sqrtf((float)(a3 >> 16));

    const int lane = t & 63;
    #pragma unroll
    for (int off = 32; off > 0; off >>= 1) vsum += __shfl_down(vsum, off, 64);
    if (lane == 0) wsum[t >> 6] = vsum;
    __syncthreads();
    if (t == 0) {
        float s = 0.f;
        #pragma unroll
        for (int k = 0; k < 8; ++k) s += wsum[k];
        partial[blk] = s;
    }
}

// ---------------------------------------------------------------------------
// Kernel C: single-block deterministic final sum (R7-proven tail).
// ---------------------------------------------------------------------------
__global__ __launch_bounds__(256) void bl_final(const float* __restrict__ partial,
                                                float* __restrict__ out) {
    __shared__ double sd[256];
    double s = (double)partial[threadIdx.x] + (double)partial[threadIdx.x + 256];
    sd[threadIdx.x] = s;
    __syncthreads();
    for (int str = 128; str > 0; str >>= 1) {
        if (threadIdx.x < str) sd[threadIdx.x] += sd[threadIdx.x + str];
        __syncthreads();
    }
    if (threadIdx.x == 0) out[0] = (float)(sd[0] / (double)NTOT);
}

// ---------------------------------------------------------------------------
extern "C" void kernel_launch(void* const* d_in, const int* in_sizes, int n_in,
                              void* d_out, int out_size, void* d_ws, size_t ws_size,
                              hipStream_t stream) {
    const float* pred = (const float*)d_in[0];
    const int*   tgt  = (const int*)d_in[1];
    float* out     = (float*)d_out;
    u16*   dsqT    = (u16*)d_ws;                         // NTOT u16 (4 MB)
    float* probT   = (float*)((char*)d_ws + (size_t)NTOT * sizeof(u16));  // 8 MB
    float* partial = probT + NTOT;                       // NBLK floats

    hipLaunchKernelGGL(edt_wh_prob,  dim3(NBLK), dim3(512), 0, stream,
                       tgt, pred, dsqT, probT);
    hipLaunchKernelGGL(edt_d_reduce, dim3(NBLK), dim3(512), 0, stream,
                       dsqT, probT, partial);
    hipLaunchKernelGGL(bl_final,     dim3(1),    dim3(256), 0, stream,
                       partial, out);
}